// Round 1
// baseline (6736.834 us; speedup 1.0000x reference)
//
#include <hip/hip_runtime.h>
#include <hip/hip_bf16.h>

constexpr int F = 128, H1 = 64, H2 = 32, K11 = 3;

// C[M x HH] = A[M x FF] @ W[FF x HH], fp32. W staged in LDS, one row per thread,
// LDS reads are wave-broadcast (all lanes same address -> conflict-free).
template<int FF, int HH>
__launch_bounds__(256)
__global__ void gemm_kernel(const float* __restrict__ A, const float* __restrict__ W,
                            float* __restrict__ C, int M) {
    __shared__ float Ws[FF * HH];
    const int tid = threadIdx.x;
    for (int i = tid * 4; i < FF * HH; i += 256 * 4)
        *reinterpret_cast<float4*>(&Ws[i]) = *reinterpret_cast<const float4*>(&W[i]);
    __syncthreads();

    const int row = blockIdx.x * 256 + tid;
    if (row >= M) return;

    float acc[HH];
#pragma unroll
    for (int j = 0; j < HH; ++j) acc[j] = 0.f;

    const float* a = A + (size_t)row * FF;
    for (int k = 0; k < FF; k += 4) {
        const float4 av = *reinterpret_cast<const float4*>(&a[k]);
        const float as[4] = {av.x, av.y, av.z, av.w};
#pragma unroll
        for (int kk = 0; kk < 4; ++kk) {
            const float* wr = &Ws[(k + kk) * HH];
#pragma unroll
            for (int j = 0; j < HH; j += 4) {
                const float4 wv = *reinterpret_cast<const float4*>(&wr[j]);
                acc[j + 0] = fmaf(as[kk], wv.x, acc[j + 0]);
                acc[j + 1] = fmaf(as[kk], wv.y, acc[j + 1]);
                acc[j + 2] = fmaf(as[kk], wv.z, acc[j + 2]);
                acc[j + 3] = fmaf(as[kk], wv.w, acc[j + 3]);
            }
        }
    }

    float* c = C + (size_t)row * HH;
#pragma unroll
    for (int j = 0; j < HH; j += 4) {
        float4 v; v.x = acc[j]; v.y = acc[j + 1]; v.z = acc[j + 2]; v.w = acc[j + 3];
        *reinterpret_cast<float4*>(&c[j]) = v;
    }
}

// out[rows[e]] += vals[e] * X[cols[e]] ; HH/4 threads per edge, float4 gather,
// per-float atomicAdd scatter.
template<int HH>
__global__ void spmm_atomic_kernel(const int* __restrict__ rows, const int* __restrict__ cols,
                                   const float* __restrict__ vals, const float* __restrict__ X,
                                   float* __restrict__ out, int E) {
    constexpr int T = HH / 4;
    const long long g = (long long)blockIdx.x * blockDim.x + threadIdx.x;
    const int e = (int)(g / T);
    if (e >= E) return;
    const int part = (int)(g % T);

    const int r = rows[e];
    const int c = cols[e];
    const float v = vals[e];
    const float4 x = *reinterpret_cast<const float4*>(&X[(size_t)c * HH + part * 4]);
    float* o = out + (size_t)r * HH + part * 4;
    atomicAdd(o + 0, v * x.x);
    atomicAdd(o + 1, v * x.y);
    atomicAdd(o + 2, v * x.z);
    atomicAdd(o + 3, v * x.w);
}

__global__ void relu_kernel(float* __restrict__ x, int n4) {
    for (int i = blockIdx.x * blockDim.x + threadIdx.x; i < n4;
         i += gridDim.x * blockDim.x) {
        float4 v = reinterpret_cast<float4*>(x)[i];
        v.x = fmaxf(v.x, 0.f); v.y = fmaxf(v.y, 0.f);
        v.z = fmaxf(v.z, 0.f); v.w = fmaxf(v.w, 0.f);
        reinterpret_cast<float4*>(x)[i] = v;
    }
}

extern "C" void kernel_launch(void* const* d_in, const int* in_sizes, int n_in,
                              void* d_out, int out_size, void* d_ws, size_t ws_size,
                              hipStream_t stream) {
    const float* feat0 = (const float*)d_in[0];
    const float* feat1 = (const float*)d_in[1];
    const int*   e00_row = (const int*)d_in[2];
    const int*   e00_col = (const int*)d_in[3];
    const float* e00_val = (const float*)d_in[4];
    const int*   e01_row = (const int*)d_in[5];
    const int*   e01_col = (const int*)d_in[6];
    const float* e01_val = (const float*)d_in[7];
    const int*   e10_row = (const int*)d_in[8];
    const int*   e10_col = (const int*)d_in[9];
    const float* e10_val = (const float*)d_in[10];
    const int*   e11_row = (const int*)d_in[11];
    const int*   e11_col = (const int*)d_in[12];
    const float* e11_val = (const float*)d_in[13];
    const float* W1_00 = (const float*)d_in[14];
    const float* W1_01 = (const float*)d_in[15];
    const float* W1_10 = (const float*)d_in[16];
    const float* W1_11 = (const float*)d_in[17];
    const float* W2_00 = (const float*)d_in[18];
    const float* W2_01 = (const float*)d_in[19];
    const float* W2_10 = (const float*)d_in[20];
    const float* W2_11 = (const float*)d_in[21];

    const int N0  = in_sizes[0] / F;
    const int N1  = in_sizes[1] / F;
    const int E00 = in_sizes[2];
    const int E01 = in_sizes[5];
    const int E10 = in_sizes[8];
    const int E11 = in_sizes[11] / K11;

    float* ws = (float*)d_ws;
    float* h0 = ws;                          // N0*H1
    float* h1 = h0 + (size_t)N0 * H1;        // N1*H1
    float* g  = h1 + (size_t)N1 * H1;        // scratch, N0*H1 floats max
    float* out = (float*)d_out;
    float* z0 = out;                         // N0*H2
    float* z1 = out + (size_t)N0 * H2;       // N1*H2

    hipMemsetAsync(h0, 0, (size_t)N0 * H1 * sizeof(float), stream);
    hipMemsetAsync(h1, 0, (size_t)N1 * H1 * sizeof(float), stream);
    hipMemsetAsync(d_out, 0, (size_t)out_size * sizeof(float), stream);

    auto gemmL1 = [&](const float* A, const float* W, float* C, int M) {
        gemm_kernel<F, H1><<<(M + 255) / 256, 256, 0, stream>>>(A, W, C, M);
    };
    auto gemmL2 = [&](const float* A, const float* W, float* C, int M) {
        gemm_kernel<H1, H2><<<(M + 255) / 256, 256, 0, stream>>>(A, W, C, M);
    };
    auto spmmL1 = [&](const int* r, const int* c, const float* v, const float* X,
                      float* o, int E) {
        long long total = (long long)E * (H1 / 4);
        spmm_atomic_kernel<H1><<<(int)((total + 255) / 256), 256, 0, stream>>>(r, c, v, X, o, E);
    };
    auto spmmL2 = [&](const int* r, const int* c, const float* v, const float* X,
                      float* o, int E) {
        long long total = (long long)E * (H2 / 4);
        spmm_atomic_kernel<H2><<<(int)((total + 255) / 256), 256, 0, stream>>>(r, c, v, X, o, E);
    };

    // ---- layer 1 -> h0 ----
    gemmL1(feat0, W1_00, g, N0);
    spmmL1(e00_row, e00_col, e00_val, g, h0, E00);
    gemmL1(feat1, W1_01, g, N1);
    spmmL1(e01_row, e01_col, e01_val, g, h0, E01);
    {
        int n4 = N0 * H1 / 4;
        relu_kernel<<<2048, 256, 0, stream>>>(h0, n4);
    }

    // ---- layer 1 -> h1 ----
    gemmL1(feat0, W1_10, g, N0);
    spmmL1(e10_row, e10_col, e10_val, g, h1, E10);
    for (int k = 0; k < K11; ++k) {
        gemmL1(feat1, W1_11 + (size_t)k * F * H1, g, N1);
        spmmL1(e11_row + (size_t)k * E11, e11_col + (size_t)k * E11,
               e11_val + (size_t)k * E11, g, h1, E11);
    }
    {
        int n4 = N1 * H1 / 4;
        relu_kernel<<<2048, 256, 0, stream>>>(h1, n4);
    }

    // ---- layer 2 -> z0 ----
    gemmL2(h0, W2_00, g, N0);
    spmmL2(e00_row, e00_col, e00_val, g, z0, E00);
    gemmL2(h1, W2_01, g, N1);
    spmmL2(e01_row, e01_col, e01_val, g, z0, E01);

    // ---- layer 2 -> z1 ----
    gemmL2(h0, W2_10, g, N0);
    spmmL2(e10_row, e10_col, e10_val, g, z1, E10);
    for (int k = 0; k < K11; ++k) {
        gemmL2(h1, W2_11 + (size_t)k * H1 * H2, g, N1);
        spmmL2(e11_row + (size_t)k * E11, e11_col + (size_t)k * E11,
               e11_val + (size_t)k * E11, g, z1, E11);
    }

    (void)n_in; (void)ws_size;
}

// Round 2
// 1578.222 us; speedup vs baseline: 4.2686x; 4.2686x over previous
//
#include <hip/hip_runtime.h>
#include <hip/hip_bf16.h>

constexpr int F = 128, H1 = 64, H2 = 32, K11 = 3;

// ---------------- dense GEMM: C[M x HH] = A[M x FF] @ W[FF x HH] ----------------
template<int FF, int HH>
__launch_bounds__(256)
__global__ void gemm_kernel(const float* __restrict__ A, const float* __restrict__ W,
                            float* __restrict__ C, int M) {
    __shared__ float Ws[FF * HH];
    const int tid = threadIdx.x;
    for (int i = tid * 4; i < FF * HH; i += 256 * 4)
        *reinterpret_cast<float4*>(&Ws[i]) = *reinterpret_cast<const float4*>(&W[i]);
    __syncthreads();

    const int row = blockIdx.x * 256 + tid;
    if (row >= M) return;

    float acc[HH];
#pragma unroll
    for (int j = 0; j < HH; ++j) acc[j] = 0.f;

    const float* a = A + (size_t)row * FF;
    for (int k = 0; k < FF; k += 4) {
        const float4 av = *reinterpret_cast<const float4*>(&a[k]);
        const float as[4] = {av.x, av.y, av.z, av.w};
#pragma unroll
        for (int kk = 0; kk < 4; ++kk) {
            const float* wr = &Ws[(k + kk) * HH];
#pragma unroll
            for (int j = 0; j < HH; j += 4) {
                const float4 wv = *reinterpret_cast<const float4*>(&wr[j]);
                acc[j + 0] = fmaf(as[kk], wv.x, acc[j + 0]);
                acc[j + 1] = fmaf(as[kk], wv.y, acc[j + 1]);
                acc[j + 2] = fmaf(as[kk], wv.z, acc[j + 2]);
                acc[j + 3] = fmaf(as[kk], wv.w, acc[j + 3]);
            }
        }
    }

    float* c = C + (size_t)row * HH;
#pragma unroll
    for (int j = 0; j < HH; j += 4) {
        float4 v; v.x = acc[j]; v.y = acc[j + 1]; v.z = acc[j + 2]; v.w = acc[j + 3];
        *reinterpret_cast<float4*>(&c[j]) = v;
    }
}

// ---------------- CSR build ----------------
__global__ void hist_kernel(const int* __restrict__ rows, int E, int* __restrict__ cnt) {
    int e = blockIdx.x * blockDim.x + threadIdx.x;
    if (e < E) atomicAdd(&cnt[rows[e]], 1);
}

struct ScanArgs {
    int* cnt[6];   // in: counts; out: cursor (= exclusive prefix)
    int* ptr[6];   // out: row_ptr (n+1)
    int  n[6];
};

__launch_bounds__(256)
__global__ void scan_kernel(ScanArgs a) {
    const int li = blockIdx.x;
    const int n = a.n[li];
    int* cnt = a.cnt[li];
    int* ptr = a.ptr[li];
    __shared__ int sums[256];
    __shared__ int carry;
    if (threadIdx.x == 0) carry = 0;
    __syncthreads();
    for (int base = 0; base < n; base += 256) {
        const int i = base + threadIdx.x;
        const int v = (i < n) ? cnt[i] : 0;
        sums[threadIdx.x] = v;
        __syncthreads();
        for (int off = 1; off < 256; off <<= 1) {
            int t = (threadIdx.x >= off) ? sums[threadIdx.x - off] : 0;
            __syncthreads();
            sums[threadIdx.x] += t;
            __syncthreads();
        }
        const int inc = sums[threadIdx.x];
        const int c = carry;
        __syncthreads();
        if (i < n) {
            const int excl = c + inc - v;
            ptr[i] = excl;
            cnt[i] = excl;   // cursor for scatter
        }
        if (threadIdx.x == 255) carry = c + sums[255];
        __syncthreads();
    }
    if (threadIdx.x == 0) ptr[n] = carry;
}

__global__ void scatter_kernel(const int* __restrict__ rows, const int* __restrict__ cols,
                               const float* __restrict__ vals, int E,
                               int* __restrict__ cur,
                               int* __restrict__ cols_s, float* __restrict__ vals_s) {
    int e = blockIdx.x * blockDim.x + threadIdx.x;
    if (e < E) {
        const int r = rows[e];
        const int pos = atomicAdd(&cur[r], 1);
        cols_s[pos] = cols[e];
        vals_s[pos] = vals[e];
    }
}

// ---------------- CSR SpMM gather: Y[row] (+)= sum_e val * X[col] ----------------
template<int HH, bool ACC, bool RELU>
__launch_bounds__(256)
__global__ void spmm_csr_kernel(const int* __restrict__ ptr, const int* __restrict__ cols,
                                const float* __restrict__ vals, const float* __restrict__ X,
                                float* __restrict__ Y, int nrows) {
    constexpr int RPB = 256 / HH;
    const int row = blockIdx.x * RPB + threadIdx.x / HH;
    const int lane = threadIdx.x % HH;
    if (row >= nrows) return;
    const int s = ptr[row], e = ptr[row + 1];
    float acc = 0.f, acc2 = 0.f;
    int i = s;
    for (; i + 1 < e; i += 2) {
        acc  = fmaf(vals[i],     X[(size_t)cols[i]     * HH + lane], acc);
        acc2 = fmaf(vals[i + 1], X[(size_t)cols[i + 1] * HH + lane], acc2);
    }
    if (i < e) acc = fmaf(vals[i], X[(size_t)cols[i] * HH + lane], acc);
    acc += acc2;
    if (ACC) acc += Y[(size_t)row * HH + lane];
    if (RELU) acc = fmaxf(acc, 0.f);
    Y[(size_t)row * HH + lane] = acc;
}

// ---------------- fallback (atomic) path kernels ----------------
template<int HH>
__global__ void spmm_atomic_kernel(const int* __restrict__ rows, const int* __restrict__ cols,
                                   const float* __restrict__ vals, const float* __restrict__ X,
                                   float* __restrict__ out, int E) {
    constexpr int T = HH / 4;
    const long long g = (long long)blockIdx.x * blockDim.x + threadIdx.x;
    const int e = (int)(g / T);
    if (e >= E) return;
    const int part = (int)(g % T);
    const int r = rows[e];
    const int c = cols[e];
    const float v = vals[e];
    const float4 x = *reinterpret_cast<const float4*>(&X[(size_t)c * HH + part * 4]);
    float* o = out + (size_t)r * HH + part * 4;
    atomicAdd(o + 0, v * x.x);
    atomicAdd(o + 1, v * x.y);
    atomicAdd(o + 2, v * x.z);
    atomicAdd(o + 3, v * x.w);
}

__global__ void relu_kernel(float* __restrict__ x, int n4) {
    for (int i = blockIdx.x * blockDim.x + threadIdx.x; i < n4;
         i += gridDim.x * blockDim.x) {
        float4 v = reinterpret_cast<float4*>(x)[i];
        v.x = fmaxf(v.x, 0.f); v.y = fmaxf(v.y, 0.f);
        v.z = fmaxf(v.z, 0.f); v.w = fmaxf(v.w, 0.f);
        reinterpret_cast<float4*>(x)[i] = v;
    }
}

extern "C" void kernel_launch(void* const* d_in, const int* in_sizes, int n_in,
                              void* d_out, int out_size, void* d_ws, size_t ws_size,
                              hipStream_t stream) {
    const float* feat0 = (const float*)d_in[0];
    const float* feat1 = (const float*)d_in[1];
    const int*   e00_row = (const int*)d_in[2];
    const int*   e00_col = (const int*)d_in[3];
    const float* e00_val = (const float*)d_in[4];
    const int*   e01_row = (const int*)d_in[5];
    const int*   e01_col = (const int*)d_in[6];
    const float* e01_val = (const float*)d_in[7];
    const int*   e10_row = (const int*)d_in[8];
    const int*   e10_col = (const int*)d_in[9];
    const float* e10_val = (const float*)d_in[10];
    const int*   e11_row = (const int*)d_in[11];
    const int*   e11_col = (const int*)d_in[12];
    const float* e11_val = (const float*)d_in[13];
    const float* W1_00 = (const float*)d_in[14];
    const float* W1_01 = (const float*)d_in[15];
    const float* W1_10 = (const float*)d_in[16];
    const float* W1_11 = (const float*)d_in[17];
    const float* W2_00 = (const float*)d_in[18];
    const float* W2_01 = (const float*)d_in[19];
    const float* W2_10 = (const float*)d_in[20];
    const float* W2_11 = (const float*)d_in[21];

    const int N0  = in_sizes[0] / F;
    const int N1  = in_sizes[1] / F;
    const int E00 = in_sizes[2];
    const int E01 = in_sizes[5];
    const int E10 = in_sizes[8];
    const int E11 = in_sizes[11] / K11;

    float* out = (float*)d_out;
    float* z0 = out;
    float* z1 = out + (size_t)N0 * H2;

    // ---- workspace layout ----
    float* ws = (float*)d_ws;
    size_t off = 0;
    float* h0 = ws + off; off += (size_t)N0 * H1;
    float* h1 = ws + off; off += (size_t)N1 * H1;
    float* g  = ws + off; off += (size_t)N0 * H1;

    int* iw = (int*)(ws + off);
    size_t ioff = 0;
    // counts (contiguous -> one memset), reused as cursors after scan
    int* c00  = iw + ioff; ioff += N0;
    int* c01  = iw + ioff; ioff += N0;
    int* c10  = iw + ioff; ioff += N1;
    int* c11[K11];
    for (int k = 0; k < K11; ++k) { c11[k] = iw + ioff; ioff += N1; }
    const size_t cnt_total = ioff;
    // row_ptrs
    int* p00 = iw + ioff; ioff += N0 + 1;
    int* p01 = iw + ioff; ioff += N0 + 1;
    int* p10 = iw + ioff; ioff += N1 + 1;
    int* p11[K11];
    for (int k = 0; k < K11; ++k) { p11[k] = iw + ioff; ioff += N1 + 1; }
    // sorted cols
    int* sc00 = iw + ioff; ioff += E00;
    int* sc01 = iw + ioff; ioff += E01;
    int* sc10 = iw + ioff; ioff += E10;
    int* sc11[K11];
    for (int k = 0; k < K11; ++k) { sc11[k] = iw + ioff; ioff += E11; }
    // sorted vals
    float* fv = (float*)(iw + ioff);
    size_t foff = 0;
    float* sv00 = fv + foff; foff += E00;
    float* sv01 = fv + foff; foff += E01;
    float* sv10 = fv + foff; foff += E10;
    float* sv11[K11];
    for (int k = 0; k < K11; ++k) { sv11[k] = fv + foff; foff += E11; }

    const size_t required = (off + ioff + foff) * sizeof(float);

    if (ws_size < required) {
        // -------- fallback: atomic path (known-good round-0 behavior) --------
        hipMemsetAsync(h0, 0, (size_t)N0 * H1 * sizeof(float), stream);
        hipMemsetAsync(h1, 0, (size_t)N1 * H1 * sizeof(float), stream);
        hipMemsetAsync(d_out, 0, (size_t)out_size * sizeof(float), stream);
        auto gemmL1 = [&](const float* A, const float* W, float* C, int M) {
            gemm_kernel<F, H1><<<(M + 255) / 256, 256, 0, stream>>>(A, W, C, M);
        };
        auto gemmL2 = [&](const float* A, const float* W, float* C, int M) {
            gemm_kernel<H1, H2><<<(M + 255) / 256, 256, 0, stream>>>(A, W, C, M);
        };
        auto spmmL1 = [&](const int* r, const int* c, const float* v, const float* X, float* o, int E) {
            long long t = (long long)E * (H1 / 4);
            spmm_atomic_kernel<H1><<<(int)((t + 255) / 256), 256, 0, stream>>>(r, c, v, X, o, E);
        };
        auto spmmL2 = [&](const int* r, const int* c, const float* v, const float* X, float* o, int E) {
            long long t = (long long)E * (H2 / 4);
            spmm_atomic_kernel<H2><<<(int)((t + 255) / 256), 256, 0, stream>>>(r, c, v, X, o, E);
        };
        gemmL1(feat0, W1_00, g, N0); spmmL1(e00_row, e00_col, e00_val, g, h0, E00);
        gemmL1(feat1, W1_01, g, N1); spmmL1(e01_row, e01_col, e01_val, g, h0, E01);
        relu_kernel<<<2048, 256, 0, stream>>>(h0, N0 * H1 / 4);
        gemmL1(feat0, W1_10, g, N0); spmmL1(e10_row, e10_col, e10_val, g, h1, E10);
        for (int k = 0; k < K11; ++k) {
            gemmL1(feat1, W1_11 + (size_t)k * F * H1, g, N1);
            spmmL1(e11_row + (size_t)k * E11, e11_col + (size_t)k * E11,
                   e11_val + (size_t)k * E11, g, h1, E11);
        }
        relu_kernel<<<2048, 256, 0, stream>>>(h1, N1 * H1 / 4);
        gemmL2(h0, W2_00, g, N0); spmmL2(e00_row, e00_col, e00_val, g, z0, E00);
        gemmL2(h1, W2_01, g, N1); spmmL2(e01_row, e01_col, e01_val, g, z0, E01);
        gemmL2(h0, W2_10, g, N0); spmmL2(e10_row, e10_col, e10_val, g, z1, E10);
        for (int k = 0; k < K11; ++k) {
            gemmL2(h1, W2_11 + (size_t)k * H1 * H2, g, N1);
            spmmL2(e11_row + (size_t)k * E11, e11_col + (size_t)k * E11,
                   e11_val + (size_t)k * E11, g, z1, E11);
        }
        return;
    }

    // -------- CSR build (once; reused by both layers) --------
    hipMemsetAsync(iw, 0, cnt_total * sizeof(int), stream);
    auto hist = [&](const int* rows, int E, int* cnt) {
        hist_kernel<<<(E + 255) / 256, 256, 0, stream>>>(rows, E, cnt);
    };
    hist(e00_row, E00, c00);
    hist(e01_row, E01, c01);
    hist(e10_row, E10, c10);
    for (int k = 0; k < K11; ++k) hist(e11_row + (size_t)k * E11, E11, c11[k]);

    ScanArgs sa;
    sa.cnt[0] = c00; sa.ptr[0] = p00; sa.n[0] = N0;
    sa.cnt[1] = c01; sa.ptr[1] = p01; sa.n[1] = N0;
    sa.cnt[2] = c10; sa.ptr[2] = p10; sa.n[2] = N1;
    for (int k = 0; k < K11; ++k) { sa.cnt[3 + k] = c11[k]; sa.ptr[3 + k] = p11[k]; sa.n[3 + k] = N1; }
    scan_kernel<<<6, 256, 0, stream>>>(sa);

    auto scat = [&](const int* r, const int* c, const float* v, int E,
                    int* cur, int* cs, float* vs) {
        scatter_kernel<<<(E + 255) / 256, 256, 0, stream>>>(r, c, v, E, cur, cs, vs);
    };
    scat(e00_row, e00_col, e00_val, E00, c00, sc00, sv00);
    scat(e01_row, e01_col, e01_val, E01, c01, sc01, sv01);
    scat(e10_row, e10_col, e10_val, E10, c10, sc10, sv10);
    for (int k = 0; k < K11; ++k)
        scat(e11_row + (size_t)k * E11, e11_col + (size_t)k * E11,
             e11_val + (size_t)k * E11, E11, c11[k], sc11[k], sv11[k]);

    // -------- main sequence --------
    auto gemmL1 = [&](const float* A, const float* W, float* C, int M) {
        gemm_kernel<F, H1><<<(M + 255) / 256, 256, 0, stream>>>(A, W, C, M);
    };
    auto gemmL2 = [&](const float* A, const float* W, float* C, int M) {
        gemm_kernel<H1, H2><<<(M + 255) / 256, 256, 0, stream>>>(A, W, C, M);
    };
    auto spmm1 = [&](const int* ptr, const int* cs, const float* vs, const float* X,
                     float* Y, int nrows, bool accRelu, bool relu) {
        const int grid = (nrows + 3) / 4;
        if (!accRelu)      spmm_csr_kernel<H1, false, false><<<grid, 256, 0, stream>>>(ptr, cs, vs, X, Y, nrows);
        else if (relu)     spmm_csr_kernel<H1, true,  true ><<<grid, 256, 0, stream>>>(ptr, cs, vs, X, Y, nrows);
        else               spmm_csr_kernel<H1, true,  false><<<grid, 256, 0, stream>>>(ptr, cs, vs, X, Y, nrows);
    };
    auto spmm2 = [&](const int* ptr, const int* cs, const float* vs, const float* X,
                     float* Y, int nrows, bool acc) {
        const int grid = (nrows + 7) / 8;
        if (!acc) spmm_csr_kernel<H2, false, false><<<grid, 256, 0, stream>>>(ptr, cs, vs, X, Y, nrows);
        else      spmm_csr_kernel<H2, true,  false><<<grid, 256, 0, stream>>>(ptr, cs, vs, X, Y, nrows);
    };

    // layer 1 -> h0 = relu(e00 @ (feat0 W1_00) + e01 @ (feat1 W1_01))
    gemmL1(feat0, W1_00, g, N0);
    spmm1(p00, sc00, sv00, g, h0, N0, false, false);
    gemmL1(feat1, W1_01, g, N1);
    spmm1(p01, sc01, sv01, g, h0, N0, true, true);

    // layer 1 -> h1 = relu(e10 @ (feat0 W1_10) + sum_k e11_k @ (feat1 W1_11k))
    gemmL1(feat0, W1_10, g, N0);
    spmm1(p10, sc10, sv10, g, h1, N1, false, false);
    for (int k = 0; k < K11; ++k) {
        gemmL1(feat1, W1_11 + (size_t)k * F * H1, g, N1);
        spmm1(p11[k], sc11[k], sv11[k], g, h1, N1, true, k == K11 - 1);
    }

    // layer 2 -> z0
    gemmL2(h0, W2_00, g, N0);
    spmm2(p00, sc00, sv00, g, z0, N0, false);
    gemmL2(h1, W2_01, g, N1);
    spmm2(p01, sc01, sv01, g, z0, N0, true);

    // layer 2 -> z1
    gemmL2(h0, W2_10, g, N0);
    spmm2(p10, sc10, sv10, g, z1, N1, false);
    for (int k = 0; k < K11; ++k) {
        gemmL2(h1, W2_11 + (size_t)k * H1 * H2, g, N1);
        spmm2(p11[k], sc11[k], sv11[k], g, z1, N1, true);
    }

    (void)n_in; (void)out_size; (void)ws_size;
}

// Round 3
// 1049.835 us; speedup vs baseline: 6.4170x; 1.5033x over previous
//
#include <hip/hip_runtime.h>
#include <hip/hip_bf16.h>

constexpr int F = 128, H1 = 64, H2 = 32, K11 = 3;

// ---------------- dense GEMM: C[M x HH] = A[M x FF] @ W[FF x HH] ----------------
// TPR threads cooperate on one row, each computing HH/TPR outputs.
template<int FF, int HH, int TPR, bool BATCH>
__launch_bounds__(256)
__global__ void gemm_kernel(const float* __restrict__ A, const float* __restrict__ W,
                            float* __restrict__ C, int M) {
    if (BATCH) {
        W += (size_t)blockIdx.y * FF * HH;
        C += (size_t)blockIdx.y * (size_t)M * HH;
    }
    __shared__ float Ws[FF * HH];
    const int tid = threadIdx.x;
    for (int i = tid * 4; i < FF * HH; i += 256 * 4)
        *reinterpret_cast<float4*>(&Ws[i]) = *reinterpret_cast<const float4*>(&W[i]);
    __syncthreads();

    constexpr int CPT = HH / TPR;   // columns per thread
    const int t = blockIdx.x * 256 + tid;
    const int row = t / TPR;
    const int sub = t % TPR;
    if (row >= M) return;

    float acc[CPT];
#pragma unroll
    for (int j = 0; j < CPT; ++j) acc[j] = 0.f;

    const float* a = A + (size_t)row * FF;
    for (int k = 0; k < FF; k += 4) {
        const float4 av = *reinterpret_cast<const float4*>(&a[k]);
        const float as[4] = {av.x, av.y, av.z, av.w};
#pragma unroll
        for (int kk = 0; kk < 4; ++kk) {
            const float* wr = &Ws[(k + kk) * HH + sub * CPT];
#pragma unroll
            for (int j = 0; j < CPT; j += 4) {
                const float4 wv = *reinterpret_cast<const float4*>(&wr[j]);
                acc[j + 0] = fmaf(as[kk], wv.x, acc[j + 0]);
                acc[j + 1] = fmaf(as[kk], wv.y, acc[j + 1]);
                acc[j + 2] = fmaf(as[kk], wv.z, acc[j + 2]);
                acc[j + 3] = fmaf(as[kk], wv.w, acc[j + 3]);
            }
        }
    }

    float* c = C + (size_t)row * HH + sub * CPT;
#pragma unroll
    for (int j = 0; j < CPT; j += 4) {
        float4 v; v.x = acc[j]; v.y = acc[j + 1]; v.z = acc[j + 2]; v.w = acc[j + 3];
        *reinterpret_cast<float4*>(&c[j]) = v;
    }
}

// ---------------- CSR build ----------------
__global__ void hist_kernel(const int* __restrict__ rows, int E, int* __restrict__ cnt) {
    int e = blockIdx.x * blockDim.x + threadIdx.x;
    if (e < E) atomicAdd(&cnt[rows[e]], 1);
}
// e11: blockIdx.y = relation k; counts at cnt + k*N, rows at rows + k*E
__global__ void hist_k_kernel(const int* __restrict__ rows, int E, int N, int* __restrict__ cnt) {
    int e = blockIdx.x * blockDim.x + threadIdx.x;
    const int k = blockIdx.y;
    if (e < E) atomicAdd(&cnt[(size_t)k * N + rows[(size_t)k * E + e]], 1);
}

// global exclusive scan over Lcap ints (Lcap multiple of 1024): 3 kernels
__launch_bounds__(256)
__global__ void scan1_kernel(const int* __restrict__ cnt, int* __restrict__ bsums) {
    __shared__ int lds[256];
    const int tid = threadIdx.x;
    const int4 v = *reinterpret_cast<const int4*>(&cnt[blockIdx.x * 1024 + tid * 4]);
    lds[tid] = v.x + v.y + v.z + v.w;
    __syncthreads();
    for (int off = 128; off > 0; off >>= 1) {
        if (tid < off) lds[tid] += lds[tid + off];
        __syncthreads();
    }
    if (tid == 0) bsums[blockIdx.x] = lds[0];
}

__launch_bounds__(256)
__global__ void scan2_kernel(const int* __restrict__ bsums, int* __restrict__ bofs, int nb) {
    __shared__ int lds[256];
    const int t = threadIdx.x;
    const int v = (t < nb) ? bsums[t] : 0;
    lds[t] = v;
    __syncthreads();
    for (int off = 1; off < 256; off <<= 1) {
        int a = (t >= off) ? lds[t - off] : 0;
        __syncthreads();
        lds[t] += a;
        __syncthreads();
    }
    if (t < nb) bofs[t] = lds[t] - v;
}

__launch_bounds__(256)
__global__ void scan3_kernel(const int* __restrict__ cnt, const int* __restrict__ bofs,
                             int* __restrict__ ptr, int* __restrict__ cur) {
    __shared__ int lds[256];
    const int tid = threadIdx.x;
    const int i = blockIdx.x * 1024 + tid * 4;
    const int4 v = *reinterpret_cast<const int4*>(&cnt[i]);
    const int s = v.x + v.y + v.z + v.w;
    lds[tid] = s;
    __syncthreads();
    for (int off = 1; off < 256; off <<= 1) {
        int a = (tid >= off) ? lds[tid - off] : 0;
        __syncthreads();
        lds[tid] += a;
        __syncthreads();
    }
    const int excl = bofs[blockIdx.x] + lds[tid] - s;
    int4 p;
    p.x = excl; p.y = p.x + v.x; p.z = p.y + v.y; p.w = p.z + v.z;
    *reinterpret_cast<int4*>(&ptr[i]) = p;
    *reinterpret_cast<int4*>(&cur[i]) = p;
}

__global__ void scatter_kernel(const int* __restrict__ rows, const int* __restrict__ cols,
                               const float* __restrict__ vals, int E,
                               int* __restrict__ cur, int2* __restrict__ cv) {
    int e = blockIdx.x * blockDim.x + threadIdx.x;
    if (e < E) {
        const int pos = atomicAdd(&cur[rows[e]], 1);
        cv[pos] = make_int2(cols[e], __float_as_int(vals[e]));
    }
}
__global__ void scatter_k_kernel(const int* __restrict__ rows, const int* __restrict__ cols,
                                 const float* __restrict__ vals, int E, int N,
                                 int* __restrict__ cur, int2* __restrict__ cv) {
    int e = blockIdx.x * blockDim.x + threadIdx.x;
    const int k = blockIdx.y;
    if (e < E) {
        const size_t ke = (size_t)k * E + e;
        const int pos = atomicAdd(&cur[(size_t)k * N + rows[ke]], 1);
        cv[pos] = make_int2(cols[ke], __float_as_int(vals[ke]));
    }
}

// ---------------- CSR SpMM gather ----------------
template<int HH, bool ACC, bool RELU>
__launch_bounds__(256)
__global__ void spmm_csr_kernel(const int* __restrict__ ptr, const int2* __restrict__ cv,
                                const float* __restrict__ X, float* __restrict__ Y, int nrows) {
    constexpr int RPB = 256 / HH;
    const int row = blockIdx.x * RPB + threadIdx.x / HH;
    const int lane = threadIdx.x % HH;
    if (row >= nrows) return;
    const int s = ptr[row], e = ptr[row + 1];
    float a0 = 0.f, a1 = 0.f, a2 = 0.f, a3 = 0.f;
    int i = s;
    for (; i + 3 < e; i += 4) {
        const int2 c0 = cv[i], c1 = cv[i + 1], c2 = cv[i + 2], c3 = cv[i + 3];
        a0 = fmaf(__int_as_float(c0.y), X[(size_t)c0.x * HH + lane], a0);
        a1 = fmaf(__int_as_float(c1.y), X[(size_t)c1.x * HH + lane], a1);
        a2 = fmaf(__int_as_float(c2.y), X[(size_t)c2.x * HH + lane], a2);
        a3 = fmaf(__int_as_float(c3.y), X[(size_t)c3.x * HH + lane], a3);
    }
    for (; i < e; ++i) {
        const int2 c = cv[i];
        a0 = fmaf(__int_as_float(c.y), X[(size_t)c.x * HH + lane], a0);
    }
    float acc = (a0 + a1) + (a2 + a3);
    if (ACC) acc += Y[(size_t)row * HH + lane];
    if (RELU) acc = fmaxf(acc, 0.f);
    Y[(size_t)row * HH + lane] = acc;
}

// multi-relation: acc over k of relation-k edges gathered from X + k*Xstride
template<int HH, bool ACC, bool RELU>
__launch_bounds__(256)
__global__ void spmm_multi_kernel(const int* __restrict__ ptr, int strideN, int nrel,
                                  const int2* __restrict__ cv,
                                  const float* __restrict__ X, size_t Xstride,
                                  float* __restrict__ Y, int nrows) {
    constexpr int RPB = 256 / HH;
    const int row = blockIdx.x * RPB + threadIdx.x / HH;
    const int lane = threadIdx.x % HH;
    if (row >= nrows) return;
    float a0 = 0.f, a1 = 0.f, a2 = 0.f, a3 = 0.f;
    for (int k = 0; k < nrel; ++k) {
        const int s = ptr[(size_t)k * strideN + row], e = ptr[(size_t)k * strideN + row + 1];
        const float* Xk = X + (size_t)k * Xstride;
        int i = s;
        for (; i + 3 < e; i += 4) {
            const int2 c0 = cv[i], c1 = cv[i + 1], c2 = cv[i + 2], c3 = cv[i + 3];
            a0 = fmaf(__int_as_float(c0.y), Xk[(size_t)c0.x * HH + lane], a0);
            a1 = fmaf(__int_as_float(c1.y), Xk[(size_t)c1.x * HH + lane], a1);
            a2 = fmaf(__int_as_float(c2.y), Xk[(size_t)c2.x * HH + lane], a2);
            a3 = fmaf(__int_as_float(c3.y), Xk[(size_t)c3.x * HH + lane], a3);
        }
        for (; i < e; ++i) {
            const int2 c = cv[i];
            a0 = fmaf(__int_as_float(c.y), Xk[(size_t)c.x * HH + lane], a0);
        }
    }
    float acc = (a0 + a1) + (a2 + a3);
    if (ACC) acc += Y[(size_t)row * HH + lane];
    if (RELU) acc = fmaxf(acc, 0.f);
    Y[(size_t)row * HH + lane] = acc;
}

// ---------------- fallback (atomic) path kernels ----------------
template<int HH>
__global__ void spmm_atomic_kernel(const int* __restrict__ rows, const int* __restrict__ cols,
                                   const float* __restrict__ vals, const float* __restrict__ X,
                                   float* __restrict__ out, int E) {
    constexpr int T = HH / 4;
    const long long g = (long long)blockIdx.x * blockDim.x + threadIdx.x;
    const int e = (int)(g / T);
    if (e >= E) return;
    const int part = (int)(g % T);
    const int r = rows[e];
    const int c = cols[e];
    const float v = vals[e];
    const float4 x = *reinterpret_cast<const float4*>(&X[(size_t)c * HH + part * 4]);
    float* o = out + (size_t)r * HH + part * 4;
    atomicAdd(o + 0, v * x.x);
    atomicAdd(o + 1, v * x.y);
    atomicAdd(o + 2, v * x.z);
    atomicAdd(o + 3, v * x.w);
}

__global__ void relu_kernel(float* __restrict__ x, int n4) {
    for (int i = blockIdx.x * blockDim.x + threadIdx.x; i < n4;
         i += gridDim.x * blockDim.x) {
        float4 v = reinterpret_cast<float4*>(x)[i];
        v.x = fmaxf(v.x, 0.f); v.y = fmaxf(v.y, 0.f);
        v.z = fmaxf(v.z, 0.f); v.w = fmaxf(v.w, 0.f);
        reinterpret_cast<float4*>(x)[i] = v;
    }
}

extern "C" void kernel_launch(void* const* d_in, const int* in_sizes, int n_in,
                              void* d_out, int out_size, void* d_ws, size_t ws_size,
                              hipStream_t stream) {
    const float* feat0 = (const float*)d_in[0];
    const float* feat1 = (const float*)d_in[1];
    const int*   e00_row = (const int*)d_in[2];
    const int*   e00_col = (const int*)d_in[3];
    const float* e00_val = (const float*)d_in[4];
    const int*   e01_row = (const int*)d_in[5];
    const int*   e01_col = (const int*)d_in[6];
    const float* e01_val = (const float*)d_in[7];
    const int*   e10_row = (const int*)d_in[8];
    const int*   e10_col = (const int*)d_in[9];
    const float* e10_val = (const float*)d_in[10];
    const int*   e11_row = (const int*)d_in[11];
    const int*   e11_col = (const int*)d_in[12];
    const float* e11_val = (const float*)d_in[13];
    const float* W1_00 = (const float*)d_in[14];
    const float* W1_01 = (const float*)d_in[15];
    const float* W1_10 = (const float*)d_in[16];
    const float* W1_11 = (const float*)d_in[17];
    const float* W2_00 = (const float*)d_in[18];
    const float* W2_01 = (const float*)d_in[19];
    const float* W2_10 = (const float*)d_in[20];
    const float* W2_11 = (const float*)d_in[21];

    const int N0  = in_sizes[0] / F;
    const int N1  = in_sizes[1] / F;
    const int E00 = in_sizes[2];
    const int E01 = in_sizes[5];
    const int E10 = in_sizes[8];
    const int E11 = in_sizes[11] / K11;
    const long long E_total = (long long)E00 + E01 + E10 + (long long)K11 * E11;

    float* out = (float*)d_out;
    float* z0 = out;
    float* z1 = out + (size_t)N0 * H2;

    // ---- workspace layout ----
    // count-array concatenation: [c00(N0) | c01(N0) | c10(N1) | c11_0(N1) | c11_1(N1) | c11_2(N1) | pad]
    const int s00 = 0, s01 = N0, s10 = 2 * N0, s11 = 2 * N0 + N1;
    const int L = 2 * N0 + (1 + K11) * N1;          // 180000
    const int Lcap = ((L + 1 + 1023) / 1024) * 1024; // padded, multiple of 1024
    const int nb = Lcap / 1024;

    float* ws = (float*)d_ws;
    size_t off = 0;
    float* h0 = ws + off; off += (size_t)N0 * H1;
    float* h1 = ws + off; off += (size_t)N1 * H1;
    float* g  = ws + off; off += (size_t)K11 * N1 * H1;  // also covers N0*H1 (3*20000*64 > 50000*64)

    int* iw = (int*)(ws + off);
    int* counts = iw;                 // Lcap
    int* gptr   = counts + Lcap;      // Lcap (row_ptr, global positions)
    int* cur    = gptr + Lcap;        // Lcap (scatter cursors)
    int* bsums  = cur + Lcap;         // 256
    int* bofs   = bsums + 256;        // 256
    int2* cv    = (int2*)(bofs + 256);// E_total int2

    const size_t required = ((size_t)off + 3 * (size_t)Lcap + 512 + 2 * (size_t)E_total) * 4;

    if (ws_size < required) {
        // -------- fallback: atomic path --------
        float* gg = h1 + (size_t)N1 * H1;
        hipMemsetAsync(h0, 0, (size_t)N0 * H1 * sizeof(float), stream);
        hipMemsetAsync(h1, 0, (size_t)N1 * H1 * sizeof(float), stream);
        hipMemsetAsync(d_out, 0, (size_t)out_size * sizeof(float), stream);
        auto gemmL1 = [&](const float* A, const float* W, float* C, int M) {
            gemm_kernel<F, H1, 4, false><<<(M * 4 + 255) / 256, 256, 0, stream>>>(A, W, C, M);
        };
        auto gemmL2 = [&](const float* A, const float* W, float* C, int M) {
            gemm_kernel<H1, H2, 4, false><<<(M * 4 + 255) / 256, 256, 0, stream>>>(A, W, C, M);
        };
        auto spmmL1 = [&](const int* r, const int* c, const float* v, const float* X, float* o, int E) {
            long long t = (long long)E * (H1 / 4);
            spmm_atomic_kernel<H1><<<(int)((t + 255) / 256), 256, 0, stream>>>(r, c, v, X, o, E);
        };
        auto spmmL2 = [&](const int* r, const int* c, const float* v, const float* X, float* o, int E) {
            long long t = (long long)E * (H2 / 4);
            spmm_atomic_kernel<H2><<<(int)((t + 255) / 256), 256, 0, stream>>>(r, c, v, X, o, E);
        };
        gemmL1(feat0, W1_00, gg, N0); spmmL1(e00_row, e00_col, e00_val, gg, h0, E00);
        gemmL1(feat1, W1_01, gg, N1); spmmL1(e01_row, e01_col, e01_val, gg, h0, E01);
        relu_kernel<<<2048, 256, 0, stream>>>(h0, N0 * H1 / 4);
        gemmL1(feat0, W1_10, gg, N0); spmmL1(e10_row, e10_col, e10_val, gg, h1, E10);
        for (int k = 0; k < K11; ++k) {
            gemmL1(feat1, W1_11 + (size_t)k * F * H1, gg, N1);
            spmmL1(e11_row + (size_t)k * E11, e11_col + (size_t)k * E11,
                   e11_val + (size_t)k * E11, gg, h1, E11);
        }
        relu_kernel<<<2048, 256, 0, stream>>>(h1, N1 * H1 / 4);
        gemmL2(h0, W2_00, gg, N0); spmmL2(e00_row, e00_col, e00_val, gg, z0, E00);
        gemmL2(h1, W2_01, gg, N1); spmmL2(e01_row, e01_col, e01_val, gg, z0, E01);
        gemmL2(h0, W2_10, gg, N0); spmmL2(e10_row, e10_col, e10_val, gg, z1, E10);
        for (int k = 0; k < K11; ++k) {
            gemmL2(h1, W2_11 + (size_t)k * H1 * H2, gg, N1);
            spmmL2(e11_row + (size_t)k * E11, e11_col + (size_t)k * E11,
                   e11_val + (size_t)k * E11, gg, z1, E11);
        }
        return;
    }

    // -------- CSR build (global scan over concatenated counts) --------
    hipMemsetAsync(counts, 0, (size_t)Lcap * sizeof(int), stream);
    hist_kernel<<<(E00 + 255) / 256, 256, 0, stream>>>(e00_row, E00, counts + s00);
    hist_kernel<<<(E01 + 255) / 256, 256, 0, stream>>>(e01_row, E01, counts + s01);
    hist_kernel<<<(E10 + 255) / 256, 256, 0, stream>>>(e10_row, E10, counts + s10);
    hist_k_kernel<<<dim3((E11 + 255) / 256, K11), 256, 0, stream>>>(e11_row, E11, N1, counts + s11);

    scan1_kernel<<<nb, 256, 0, stream>>>(counts, bsums);
    scan2_kernel<<<1, 256, 0, stream>>>(bsums, bofs, nb);
    scan3_kernel<<<nb, 256, 0, stream>>>(counts, bofs, gptr, cur);

    scatter_kernel<<<(E00 + 255) / 256, 256, 0, stream>>>(e00_row, e00_col, e00_val, E00, cur + s00, cv);
    scatter_kernel<<<(E01 + 255) / 256, 256, 0, stream>>>(e01_row, e01_col, e01_val, E01, cur + s01, cv);
    scatter_kernel<<<(E10 + 255) / 256, 256, 0, stream>>>(e10_row, e10_col, e10_val, E10, cur + s10, cv);
    scatter_k_kernel<<<dim3((E11 + 255) / 256, K11), 256, 0, stream>>>(e11_row, e11_col, e11_val, E11, N1, cur + s11, cv);

    // -------- main sequence --------
    auto gemmL1 = [&](const float* A, const float* W, float* C, int M) {
        gemm_kernel<F, H1, 4, false><<<(M * 4 + 255) / 256, 256, 0, stream>>>(A, W, C, M);
    };
    auto gemmL2 = [&](const float* A, const float* W, float* C, int M) {
        gemm_kernel<H1, H2, 4, false><<<(M * 4 + 255) / 256, 256, 0, stream>>>(A, W, C, M);
    };

    // layer 1 -> h0
    gemmL1(feat0, W1_00, g, N0);
    spmm_csr_kernel<H1, false, false><<<(N0 + 3) / 4, 256, 0, stream>>>(gptr + s00, cv, g, h0, N0);
    gemmL1(feat1, W1_01, g, N1);
    spmm_csr_kernel<H1, true, true><<<(N0 + 3) / 4, 256, 0, stream>>>(gptr + s01, cv, g, h0, N0);

    // layer 1 -> h1
    gemmL1(feat0, W1_10, g, N0);
    spmm_csr_kernel<H1, false, false><<<(N1 + 3) / 4, 256, 0, stream>>>(gptr + s10, cv, g, h1, N1);
    gemm_kernel<F, H1, 4, true><<<dim3((N1 * 4 + 255) / 256, K11), 256, 0, stream>>>(feat1, W1_11, g, N1);
    spmm_multi_kernel<H1, true, true><<<(N1 + 3) / 4, 256, 0, stream>>>(
        gptr + s11, N1, K11, cv, g, (size_t)N1 * H1, h1, N1);

    // layer 2 -> z0
    gemmL2(h0, W2_00, g, N0);
    spmm_csr_kernel<H2, false, false><<<(N0 + 7) / 8, 256, 0, stream>>>(gptr + s00, cv, g, z0, N0);
    gemmL2(h1, W2_01, g, N1);
    spmm_csr_kernel<H2, true, false><<<(N0 + 7) / 8, 256, 0, stream>>>(gptr + s01, cv, g, z0, N0);

    // layer 2 -> z1
    gemmL2(h0, W2_10, g, N0);
    spmm_csr_kernel<H2, false, false><<<(N1 + 7) / 8, 256, 0, stream>>>(gptr + s10, cv, g, z1, N1);
    gemm_kernel<H1, H2, 4, true><<<dim3((N1 * 4 + 255) / 256, K11), 256, 0, stream>>>(h1, W2_11, g, N1);
    spmm_multi_kernel<H2, true, false><<<(N1 + 7) / 8, 256, 0, stream>>>(
        gptr + s11, N1, K11, cv, g, (size_t)N1 * H2, z1, N1);

    (void)n_in; (void)out_size; (void)ws_size;
}